// Round 14
// baseline (4682.334 us; speedup 1.0000x reference)
//
#include <hip/hip_runtime.h>
#include <cstdint>
#include <cstddef>

typedef unsigned short ushort_t;
typedef unsigned int uint_t;
typedef __attribute__((ext_vector_type(8))) __bf16 bf16x8;
typedef __attribute__((ext_vector_type(4))) float f32x4;
typedef __attribute__((ext_vector_type(2))) unsigned int u32x2;

static constexpr int T_STEPS = 512;
static constexpr int BATCH   = 256;
static constexpr int OBS_D   = 64;
static constexpr int ACT_D   = 8;
static constexpr int HID_D   = 1024;
static constexpr int CELL_D  = 512;
static constexpr int GATE_D  = 4 * CELL_D;   // 2048
static constexpr int SCAN_BLOCKS = 256;      // 8 batch-groups x 32 cell-slices
static constexpr int WORK_BLOCKS = 256;      // co-resident GEMM/mean workers

__device__ __forceinline__ float bf2f(ushort_t s) {
    uint_t u = ((uint_t)s) << 16;
    float f;
    __builtin_memcpy(&f, &u, 4);
    return f;
}
__device__ __forceinline__ ushort_t f2bf(float x) {
    uint_t u;
    __builtin_memcpy(&u, &x, 4);
    u += 0x7fffu + ((u >> 16) & 1u);   // RNE
    return (ushort_t)(u >> 16);
}

// ---- fast transcendentals (v_exp_f32 / v_rcp_f32; exact at saturation) ----
__device__ __forceinline__ float sigmoid_fast(float x) {
    return __builtin_amdgcn_rcpf(1.f + __expf(-x));
}
__device__ __forceinline__ float tanh_fast(float x) {
    const float e = __expf(-2.f * fabsf(x));          // in [0,1]
    const float r = (1.f - e) * __builtin_amdgcn_rcpf(1.f + e);
    return copysignf(r, x);
}

// ---- f32 -> bf16 bulk convert (8/thread; n multiple of 2048) ----
__global__ __launch_bounds__(256)
void cvt_f32_bf16(const float* __restrict__ in, ushort_t* __restrict__ out)
{
    const size_t i = ((size_t)blockIdx.x * 256 + threadIdx.x) * 8;
    const float4 v0 = *(const float4*)(in + i);
    const float4 v1 = *(const float4*)(in + i + 4);
    uint4 p;
    p.x = (uint_t)f2bf(v0.x) | ((uint_t)f2bf(v0.y) << 16);
    p.y = (uint_t)f2bf(v0.z) | ((uint_t)f2bf(v0.w) << 16);
    p.z = (uint_t)f2bf(v1.x) | ((uint_t)f2bf(v1.y) << 16);
    p.w = (uint_t)f2bf(v1.z) | ((uint_t)f2bf(v1.w) << 16);
    *(uint4*)(out + i) = p;
}

// Gate-major [4*C][K] f32 -> cell-major permuted bf16: Wp[P=c*4+g][k]
__global__ __launch_bounds__(256)
void permute_gate_rows(const float* __restrict__ W, ushort_t* __restrict__ Wp, int K)
{
    const int P = blockIdx.x;               // 0..2047
    const int c = P >> 2, g = P & 3;
    const float* src = W + (size_t)(g * CELL_D + c) * K;
    ushort_t* dst = Wp + (size_t)P * K;
    for (int k = threadIdx.x; k < K; k += 256) dst[k] = f2bf(src[k]);
}

// W_hh permute for the 256-block scan's lane->cell mapping:
// global row j*64 + t*16 + q*4 + r  <-  W_hh[gate r][cell j*16 + t*4 + q]
__global__ __launch_bounds__(256)
void permute_whh_rows(const float* __restrict__ W, ushort_t* __restrict__ Wp, int K)
{
    const int P = blockIdx.x;               // 0..2047
    const int blk = P >> 6, rl = P & 63;
    const int t = rl >> 4, qq = (rl >> 2) & 3, r = rl & 3;
    const float* src = W + (size_t)(r * CELL_D + blk * 16 + t * 4 + qq) * K;
    ushort_t* dst = Wp + (size_t)P * K;
    for (int k = threadIdx.x; k < K; k += 256) dst[k] = f2bf(src[k]);
}

__global__ __launch_bounds__(256)
void permute_bias(const float* __restrict__ b, float* __restrict__ bp)
{
    const int P = blockIdx.x * 256 + threadIdx.x;   // grid 8
    bp[P] = b[(P & 3) * CELL_D + (P >> 2)];
}

// ---- MFMA bf16 GEMM (standalone, 256 thr): C[m][n] = A·B^T + bias ----
template<int OUT_MODE>
__global__ __launch_bounds__(256)
void gemm_mfma_nt(const ushort_t* __restrict__ A, const ushort_t* __restrict__ B,
                  const float* __restrict__ bias, void* __restrict__ out_,
                  int N, int K)
{
    __shared__ __align__(16) ushort_t As[128 * 32];
    __shared__ __align__(16) ushort_t Bs[128 * 32];
    const int tid  = threadIdx.x;
    const int lane = tid & 63;
    const int wid  = tid >> 6;
    const int wr   = (wid >> 1) * 64;
    const int wc   = (wid & 1) * 64;
    const int m0 = blockIdx.y * 128;
    const int n0 = blockIdx.x * 128;

    const int srow = tid >> 2;
    const int sv   = tid & 3;
    const int fr   = lane & 15;
    const int fo   = lane >> 4;

    f32x4 acc[4][4];
#pragma unroll
    for (int i = 0; i < 4; ++i)
#pragma unroll
        for (int j = 0; j < 4; ++j) acc[i][j] = (f32x4){0.f, 0.f, 0.f, 0.f};

    const ushort_t* Apt = A + (size_t)(m0 + srow) * K + sv * 8;
    const ushort_t* Bpt = B + (size_t)(n0 + srow) * K + sv * 8;
    uint4* As4 = (uint4*)As;
    uint4* Bs4 = (uint4*)Bs;
    const bf16x8* Af = (const bf16x8*)As;
    const bf16x8* Bf = (const bf16x8*)Bs;

    for (int k0 = 0; k0 < K; k0 += 32) {
        const uint4 a0 = *(const uint4*)(Apt + k0);
        const uint4 a1 = *(const uint4*)(Apt + (size_t)64 * K + k0);
        const uint4 b0 = *(const uint4*)(Bpt + k0);
        const uint4 b1 = *(const uint4*)(Bpt + (size_t)64 * K + k0);
        __syncthreads();
        As4[srow * 4 + sv]        = a0;
        As4[(64 + srow) * 4 + sv] = a1;
        Bs4[srow * 4 + sv]        = b0;
        Bs4[(64 + srow) * 4 + sv] = b1;
        __syncthreads();

        bf16x8 av[4], bv[4];
#pragma unroll
        for (int m = 0; m < 4; ++m) av[m] = Af[(wr + m * 16 + fr) * 4 + fo];
#pragma unroll
        for (int n = 0; n < 4; ++n) bv[n] = Bf[(wc + n * 16 + fr) * 4 + fo];
#pragma unroll
        for (int m = 0; m < 4; ++m)
#pragma unroll
            for (int n = 0; n < 4; ++n)
                acc[m][n] = __builtin_amdgcn_mfma_f32_16x16x32_bf16(
                    av[m], bv[n], acc[m][n], 0, 0, 0);
    }

#pragma unroll
    for (int n = 0; n < 4; ++n) {
        const int col = n0 + wc + n * 16 + fr;
        const float bvv = bias[col];
#pragma unroll
        for (int m = 0; m < 4; ++m) {
            const int row0 = m0 + wr + m * 16 + fo * 4;
#pragma unroll
            for (int r = 0; r < 4; ++r) {
                const float v = acc[m][n][r] + bvv;
                if constexpr (OUT_MODE == 1)
                    ((ushort_t*)out_)[(size_t)(row0 + r) * N + col] = f2bf(fmaxf(v, 0.f));
                else if constexpr (OUT_MODE == 2)
                    ((ushort_t*)out_)[(size_t)(row0 + r) * N + col] = f2bf(v);
                else
                    ((float*)out_)[(size_t)(row0 + r) * N + col] = v;
            }
        }
    }
}

// ---- h-read pipeline helpers ----
__device__ __forceinline__ void loadq1(uint4 (&d)[4], const ushort_t* hr, int base)
{
#pragma unroll
    for (int j = 0; j < 4; ++j) d[j] = *(const uint4*)(hr + (base + j) * 32);
}

__device__ __forceinline__ void compq1(const uint4 (&d)[4],
                                       const char* wsrow, int q16, int xmask,
                                       int base, f32x4& acc)
{
#pragma unroll
    for (int j = 0; j < 4; ++j) {
        bf16x8 hv;
        __builtin_memcpy(&hv, &d[j], 16);
        const int koff = ((base + j) * 64 + q16) ^ xmask;
        const bf16x8 av = *(const bf16x8*)(wsrow + koff);
        acc = __builtin_amdgcn_mfma_f32_16x16x32_bf16(av, hv, acc, 0, 0, 0);
    }
}

// ---- 512-thread GEMM tile (worker role): 128x128, 8 waves 4x2 ----
// Same per-element K-accumulation order as gemm_mfma_nt -> bit-identical.
__device__ void gemm_tile_512(const ushort_t* __restrict__ A,
                              const ushort_t* __restrict__ B,
                              const float* __restrict__ bias,
                              ushort_t* __restrict__ out,
                              int N, int K, int m0, int n0, char* sh)
{
    uint4* As4 = (uint4*)sh;                    // 128 x 4 chunks = 8 KiB
    uint4* Bs4 = (uint4*)(sh + 8192);
    const bf16x8* Af = (const bf16x8*)sh;
    const bf16x8* Bf = (const bf16x8*)(sh + 8192);
    const int tid  = threadIdx.x;
    const int lane = tid & 63;
    const int wid  = tid >> 6;
    const int wr   = (wid & 3) * 32;
    const int wc   = (wid >> 2) * 64;
    const int srow = tid >> 2;                  // 0..127
    const int sv   = tid & 3;
    const int fr   = lane & 15;
    const int fo   = lane >> 4;

    f32x4 acc[2][4];
#pragma unroll
    for (int m = 0; m < 2; ++m)
#pragma unroll
        for (int n = 0; n < 4; ++n) acc[m][n] = (f32x4){0.f, 0.f, 0.f, 0.f};

    const ushort_t* Apt = A + (size_t)(m0 + srow) * K + sv * 8;
    const ushort_t* Bpt = B + (size_t)(n0 + srow) * K + sv * 8;

    for (int k0 = 0; k0 < K; k0 += 32) {
        const uint4 a0 = *(const uint4*)(Apt + k0);
        const uint4 b0 = *(const uint4*)(Bpt + k0);
        __syncthreads();
        As4[srow * 4 + sv] = a0;
        Bs4[srow * 4 + sv] = b0;
        __syncthreads();

        bf16x8 av[2], bv[4];
#pragma unroll
        for (int m = 0; m < 2; ++m) av[m] = Af[(wr + m * 16 + fr) * 4 + fo];
#pragma unroll
        for (int n = 0; n < 4; ++n) bv[n] = Bf[(wc + n * 16 + fr) * 4 + fo];
#pragma unroll
        for (int m = 0; m < 2; ++m)
#pragma unroll
            for (int n = 0; n < 4; ++n)
                acc[m][n] = __builtin_amdgcn_mfma_f32_16x16x32_bf16(
                    av[m], bv[n], acc[m][n], 0, 0, 0);
    }

#pragma unroll
    for (int n = 0; n < 4; ++n) {
        const int col = n0 + wc + n * 16 + fr;
        const float bvv = bias[col];
#pragma unroll
        for (int m = 0; m < 2; ++m) {
            const int row0 = m0 + wr + m * 16 + fo * 4;
#pragma unroll
            for (int r = 0; r < 4; ++r)
                out[(size_t)(row0 + r) * N + col] = f2bf(acc[m][n][r] + bvv);
        }
    }
}

// ---- FUSED persistent kernel: 512 blocks x 512 threads ----
// blocks [0,256): LSTM scan chunk ci (r13 body, s_setprio(1)).
// blocks [256,512): workers — gemm2 for chunk ci+1 (E @ W_ih^T -> gx_next),
//   then mean_head for chunk ci-1. NO cross-role sync (ordering by kernel
//   boundaries). All 512 blocks co-resident (2x64KiB LDS, 16 waves/CU) ->
//   scan's flag protocol deadlock-free.
__global__ __launch_bounds__(512, 4)
void fused_scan(const ushort_t* __restrict__ gx_p,
                const ushort_t* __restrict__ Whh_p,
                const float* __restrict__ b_hh,
                const float* __restrict__ masks_c,
                const ushort_t* h_init,
                float* __restrict__ c_state,
                ushort_t* __restrict__ hid,
                float* __restrict__ hT_f32,
                int Tc, int is_last,
                uint_t* __restrict__ bar,
                int do_gemm,
                const ushort_t* __restrict__ E,
                const ushort_t* __restrict__ Wih_p,
                const float* __restrict__ bihp,
                ushort_t* __restrict__ gx_next,
                int do_mean,
                const ushort_t* __restrict__ hid_prev,
                const float* __restrict__ W_mean,
                const float* __restrict__ b_mean,
                const float* __restrict__ lstd,
                float* __restrict__ means_prev,
                float* __restrict__ logstd_prev)
{
    __shared__ __align__(16) char shmem[64 * 1024];

    if (blockIdx.x < SCAN_BLOCKS) {
        // ================= SCAN ROLE (r13 body, unchanged numerics) ========
        __builtin_amdgcn_s_setprio(1);          // favor scan over workers
        ushort_t* Ws = (ushort_t*)shmem;

        const int tid  = threadIdx.x;
        const int lane = tid & 63;
        const int w8   = tid >> 6;
        const int w    = w8 & 3;
        const int nfl  = w8 >> 2;
        const int q    = lane >> 4;
        const int s    = lane & 15;
        const int x    = blockIdx.x & 7;
        const int j    = blockIdx.x >> 3;
        const int xmask = (s & 7) << 4;
        const int q16  = q * 16;
        const int cell = j * 16 + w * 4 + q;

        for (int idx = tid; idx < 64 * 64; idx += 512) {
            const int row = idx >> 6;
            const int c16 = idx & 63;
            const uint4 v = *(const uint4*)(Whh_p + (size_t)(j * 64 + row) * CELL_D + c16 * 8);
            *(uint4*)((char*)Ws + row * 1024 + ((c16 * 16) ^ ((row & 7) << 4))) = v;
        }

        const int b = x * 32 + nfl * 16 + s;

        float creg = c_state[(size_t)b * CELL_D + cell];
        float bh[4];
#pragma unroll
        for (int r = 0; r < 4; ++r) bh[r] = b_hh[r * CELL_D + cell];

        float mv;
        uint2 gxv;
        auto prefetch_step = [&](int TL) {
            gxv = *(const uint2*)(gx_p + ((size_t)TL * BATCH + b) * GATE_D + cell * 4);
            mv  = masks_c[(size_t)TL * BATCH + b];
        };

        const char* wsrow = (const char*)Ws + (w * 16 + s) * 1024;
        __syncthreads();

        for (int tl = 0; tl < Tc; ++tl) {
            const ushort_t* hp = (tl == 0) ? h_init
                                           : hid + (size_t)(tl - 1) * BATCH * CELL_D;
            const ushort_t* hr = hp + (size_t)b * CELL_D + q * 8;

            uint64_t ready = 0;
            const uint_t tgt_in = (uint_t)tl;
            auto waitg = [&](int g) {
                const uint64_t need = 0xFFull << (g * 8);
                if ((ready & need) != need) {
                    const uint_t* fp = bar + x * 32 + (lane & 31);
                    for (;;) {
                        uint_t v;
                        asm volatile("global_load_dword %0, %1, off sc0 sc1\n\t"
                                     "s_waitcnt vmcnt(0)"
                                     : "=v"(v) : "v"(fp) : "memory");
                        ready = __ballot((int)(v >= tgt_in)) & 0xFFFFFFFFull;
                        if ((ready & need) == need) break;
                        __builtin_amdgcn_s_sleep(1);
                    }
                }
                asm volatile("" ::: "memory");
            };

            f32x4 acc = (f32x4){0.f, 0.f, 0.f, 0.f};

            uint4 A[4], B[4];
            if (tl) waitg(0);
            loadq1(A, hr, 0);
            prefetch_step(tl);
            if (tl) waitg(1);
            loadq1(B, hr, 4);
            compq1(A, wsrow, q16, xmask, 0, acc);
            if (tl) waitg(2);
            loadq1(A, hr, 8);
            compq1(B, wsrow, q16, xmask, 4, acc);
            if (tl) waitg(3);
            loadq1(B, hr, 12);
            compq1(A, wsrow, q16, xmask, 8, acc);
            compq1(B, wsrow, q16, xmask, 12, acc);

            const float keep = (mv > 0.5f) ? 0.f : 1.f;
            const ushort_t* gp = (const ushort_t*)&gxv;
            const float gi = fmaf(acc[0], keep, bf2f(gp[0]) + bh[0]);
            const float gf = fmaf(acc[1], keep, bf2f(gp[1]) + bh[1]);
            const float gg = fmaf(acc[2], keep, bf2f(gp[2]) + bh[2]);
            const float go = fmaf(acc[3], keep, bf2f(gp[3]) + bh[3]);
            const float cn = sigmoid_fast(gf) * (creg * keep)
                           + sigmoid_fast(gi) * tanh_fast(gg);
            const float hn = sigmoid_fast(go) * tanh_fast(cn);
            creg = cn;

            const uint_t hv = (uint_t)f2bf(hn);
            const uint_t vA = (uint_t)__shfl((int)hv, s + 16);
            const uint_t vB = (uint_t)__shfl((int)hv, s + 32);
            const uint_t vC = (uint_t)__shfl((int)hv, s + 48);
            if (q == 0) {
                u32x2 r0;
                r0[0] = hv | (vA << 16);
                r0[1] = vB | (vC << 16);
                ushort_t* d0 = hid + (size_t)tl * BATCH * CELL_D
                             + (size_t)b * CELL_D + j * 16 + w * 4;
                asm volatile("global_store_dwordx2 %0, %1, off sc0 sc1"
                             :: "v"(d0), "v"(r0) : "memory");
            }
            if (is_last && tl == Tc - 1)
                hT_f32[(size_t)b * CELL_D + cell] = hn;

            if (tl == Tc - 1) break;

            asm volatile("s_waitcnt vmcnt(0)" ::: "memory");
            __builtin_amdgcn_s_barrier();
            if (tid == 0) {
                const uint_t tgt = (uint_t)(tl + 1);
                asm volatile("global_store_dword %0, %1, off sc0 sc1"
                             :: "v"(bar + x * 32 + j), "v"(tgt) : "memory");
            }
        }

        c_state[(size_t)b * CELL_D + cell] = creg;
    } else {
        // ================= WORKER ROLE ====================================
        const int wbid = blockIdx.x - SCAN_BLOCKS;   // 0..255
        const int tid  = threadIdx.x;

        if (do_gemm) {
            // gemm2 for next chunk: gx_next = E @ Wih_p^T + bihp
            const int mtiles = (Tc * BATCH) / 128;
            const int tiles  = mtiles * (GATE_D / 128);
            for (int t = wbid; t < tiles; t += WORK_BLOCKS) {
                const int m0 = (t >> 4) * 128;
                const int n0 = (t & 15) * 128;
                gemm_tile_512(E, Wih_p, bihp, gx_next, GATE_D, HID_D, m0, n0, shmem);
            }
        }

        if (do_mean) {
            // mean_head for previous chunk (same per-element order as kernel)
            __syncthreads();
            float (*Wm)[516] = (float(*)[516])shmem;  // 16.5 KiB
#pragma unroll
            for (int i = 0; i < 8; ++i) {
                int idx = i * 512 + tid;
                Wm[idx >> 9][idx & 511] = W_mean[idx];
            }
            __syncthreads();
            const int r = tid >> 3, a = tid & 7;
            const int units = (Tc * BATCH) / 64;
            for (int u = wbid; u < units; u += WORK_BLOCKS) {
                const size_t m = (size_t)u * 64 + r;
                const ushort_t* hp = hid_prev + m * CELL_D;
                float acc = 0.f;
#pragma unroll 2
                for (int k8 = 0; k8 < 64; ++k8) {
                    const uint4 v = *(const uint4*)(hp + k8 * 8);
                    const ushort_t* pv = (const ushort_t*)&v;
                    const float* wv = &Wm[a][k8 * 8];
#pragma unroll
                    for (int e = 0; e < 8; ++e) acc = fmaf(bf2f(pv[e]), wv[e], acc);
                }
                means_prev[m * ACT_D + a]  = tanhf(acc + b_mean[a]);
                logstd_prev[m * ACT_D + a] = lstd[a];
            }
        }
    }
}

// means = tanh(h @ W_mean^T + b_mean); standalone (tail chunk only)
__global__ __launch_bounds__(256)
void mean_head(const ushort_t* __restrict__ hiddens, const float* __restrict__ W_mean,
               const float* __restrict__ b_mean, const float* __restrict__ log_std,
               float* __restrict__ means_out, float* __restrict__ logstd_out)
{
    __shared__ float Wm[8][516];
    const int tid = threadIdx.x;
#pragma unroll
    for (int i = 0; i < 16; ++i) {
        int idx = i * 256 + tid;
        Wm[idx >> 9][idx & 511] = W_mean[idx];
    }
    __syncthreads();
    const int r = tid >> 3, a = tid & 7;
    const size_t m = (size_t)blockIdx.x * 32 + r;
    const ushort_t* hp = hiddens + m * CELL_D;
    float acc = 0.f;
#pragma unroll 2
    for (int k8 = 0; k8 < 64; ++k8) {
        const uint4 v = *(const uint4*)(hp + k8 * 8);
        const ushort_t* pv = (const ushort_t*)&v;
        const float* wv = &Wm[a][k8 * 8];
#pragma unroll
        for (int e = 0; e < 8; ++e) acc = fmaf(bf2f(pv[e]), wv[e], acc);
    }
    means_out[m * ACT_D + a]  = tanhf(acc + b_mean[a]);
    logstd_out[m * ACT_D + a] = log_std[a];
}

extern "C" void kernel_launch(void* const* d_in, const int* in_sizes, int n_in,
                              void* d_out, int out_size, void* d_ws, size_t ws_size,
                              hipStream_t stream)
{
    const float* xs     = (const float*)d_in[0];
    const float* h0     = (const float*)d_in[1];
    const float* c0     = (const float*)d_in[2];
    const float* masks  = (const float*)d_in[3];
    const float* W_in   = (const float*)d_in[4];
    const float* b_in   = (const float*)d_in[5];
    const float* W_ih   = (const float*)d_in[6];
    const float* b_ih   = (const float*)d_in[7];
    const float* W_hh   = (const float*)d_in[8];
    const float* b_hh   = (const float*)d_in[9];
    const float* W_mean = (const float*)d_in[10];
    const float* b_mean = (const float*)d_in[11];
    const float* lstd   = (const float*)d_in[12];

    const int M = T_STEPS * BATCH;
    const size_t stateB = (size_t)BATCH * CELL_D * sizeof(float);   // 512 KiB

    const size_t szWhh  = (size_t)GATE_D * CELL_D * 2;   // 2 MiB
    const size_t szWih  = (size_t)GATE_D * HID_D * 2;    // 4 MiB
    const size_t szWin  = (size_t)HID_D * OBS_D * 2;     // 128 KiB
    const size_t szH0b  = (size_t)BATCH * CELL_D * 2;    // 256 KiB
    const size_t szBih  = (size_t)GATE_D * 4;            // 8 KiB
    const size_t szBar  = 1024;
    const size_t szXsb  = (size_t)T_STEPS * BATCH * OBS_D * 2;   // 16 MiB (full)
    const size_t fixed  = szWhh + szWih + szWin + szH0b + szBih + szBar + stateB + szXsb;

    // per-step: 2x gx (double-buffer) + 2x hid + 1x E
    const size_t gxStep  = (size_t)BATCH * GATE_D * 2;   // 1 MiB
    const size_t hidStep = (size_t)BATCH * CELL_D * 2;   // 256 KiB
    const size_t eStep   = (size_t)BATCH * HID_D * 2;    // 512 KiB
    const size_t per_tc  = 2 * gxStep + 2 * hidStep + eStep;
    int Tc = 128;
    while (Tc > 4 && fixed + per_tc * (size_t)Tc > ws_size) Tc >>= 1;
    const int chunks = T_STEPS / Tc;
    const int Mc = Tc * BATCH;

    char* p = (char*)d_ws;
    ushort_t* Whh_p = (ushort_t*)p;              p += szWhh;
    ushort_t* Wih_p = (ushort_t*)p;              p += szWih;
    ushort_t* Win_b = (ushort_t*)p;              p += szWin;
    ushort_t* h0b   = (ushort_t*)p;              p += szH0b;
    float*    bihp  = (float*)p;                 p += szBih;
    uint_t*   bar   = (uint_t*)p;                p += szBar;
    float*    c_state = (float*)p;               p += stateB;
    ushort_t* xs_b  = (ushort_t*)p;              p += szXsb;
    ushort_t* E     = (ushort_t*)p;              p += eStep * (size_t)Tc;
    ushort_t* gx0   = (ushort_t*)p;              p += gxStep * (size_t)Tc;
    ushort_t* gx1   = (ushort_t*)p;              p += gxStep * (size_t)Tc;
    ushort_t* hid0  = (ushort_t*)p;              p += hidStep * (size_t)Tc;
    ushort_t* hid1  = (ushort_t*)p;
    ushort_t* gxb[2]  = {gx0, gx1};
    ushort_t* hidb[2] = {hid0, hid1};

    float* means_out  = (float*)d_out;
    float* logstd_out = means_out + (size_t)M * ACT_D;
    float* hT_out     = logstd_out + (size_t)M * ACT_D;
    float* cT_out     = hT_out + (size_t)BATCH * CELL_D;

    // ---- one-shot converts / permutes / state init ----
    permute_whh_rows<<<GATE_D, 256, 0, stream>>>(W_hh, Whh_p, CELL_D);
    permute_gate_rows<<<GATE_D, 256, 0, stream>>>(W_ih, Wih_p, HID_D);
    cvt_f32_bf16<<<(HID_D * OBS_D) / 2048, 256, 0, stream>>>(W_in, Win_b);
    cvt_f32_bf16<<<(BATCH * CELL_D) / 2048, 256, 0, stream>>>(h0, h0b);
    permute_bias<<<GATE_D / 256, 256, 0, stream>>>(b_ih, bihp);
    hipMemcpyAsync(c_state, c0, stateB, hipMemcpyDeviceToDevice, stream);

    // convert ALL xs upfront
    cvt_f32_bf16<<<(T_STEPS * BATCH * OBS_D) / 2048, 256, 0, stream>>>(xs, xs_b);

    // chunk 0 pipeline (serial, once)
    gemm_mfma_nt<1><<<dim3(HID_D / 128, Mc / 128), 256, 0, stream>>>(
        xs_b, Win_b, b_in, E, HID_D, OBS_D);
    gemm_mfma_nt<2><<<dim3(GATE_D / 128, Mc / 128), 256, 0, stream>>>(
        E, Wih_p, bihp, gxb[0], GATE_D, HID_D);

    for (int ci = 0; ci < chunks; ++ci) {
        const int t0 = ci * Tc;
        const int do_gemm = (ci + 1 < chunks);
        const int do_mean = (ci > 0);

        if (do_gemm)   // gemm1 for next chunk (small; E consumed by workers)
            gemm_mfma_nt<1><<<dim3(HID_D / 128, Mc / 128), 256, 0, stream>>>(
                xs_b + (size_t)(t0 + Tc) * BATCH * OBS_D, Win_b, b_in, E, HID_D, OBS_D);

        hipMemsetAsync(bar, 0, 1024, stream);
        const ushort_t* h_init = (ci == 0) ? h0b
                               : hidb[(ci - 1) & 1] + (size_t)(Tc - 1) * BATCH * CELL_D;
        const int tp = (ci - 1) * Tc;
        fused_scan<<<SCAN_BLOCKS + WORK_BLOCKS, 512, 0, stream>>>(
            gxb[ci & 1], Whh_p, b_hh, masks + (size_t)t0 * BATCH, h_init,
            c_state, hidb[ci & 1], hT_out, Tc, (ci == chunks - 1) ? 1 : 0, bar,
            do_gemm, E, Wih_p, bihp, gxb[(ci + 1) & 1],
            do_mean, hidb[(ci - 1) & 1], W_mean, b_mean, lstd,
            means_out + (size_t)(do_mean ? tp : 0) * BATCH * ACT_D,
            logstd_out + (size_t)(do_mean ? tp : 0) * BATCH * ACT_D);
    }

    // tail: mean_head for the last chunk
    mean_head<<<Mc / 32, 256, 0, stream>>>(
        hidb[(chunks - 1) & 1], W_mean, b_mean, lstd,
        means_out + (size_t)(chunks - 1) * Tc * BATCH * ACT_D,
        logstd_out + (size_t)(chunks - 1) * Tc * BATCH * ACT_D);

    hipMemcpyAsync(cT_out, c_state, stateB, hipMemcpyDeviceToDevice, stream);
}

// Round 15
// 3698.419 us; speedup vs baseline: 1.2660x; 1.2660x over previous
//
#include <hip/hip_runtime.h>
#include <cstdint>
#include <cstddef>

typedef unsigned short ushort_t;
typedef unsigned int uint_t;
typedef __attribute__((ext_vector_type(8))) __bf16 bf16x8;
typedef __attribute__((ext_vector_type(4))) float f32x4;
typedef __attribute__((ext_vector_type(2))) unsigned int u32x2;

static constexpr int T_STEPS = 512;
static constexpr int BATCH   = 256;
static constexpr int OBS_D   = 64;
static constexpr int ACT_D   = 8;
static constexpr int HID_D   = 1024;
static constexpr int CELL_D  = 512;
static constexpr int GATE_D  = 4 * CELL_D;   // 2048
static constexpr int SCAN_BLOCKS = 256;      // 8 batch-groups x 32 cell-slices

__device__ __forceinline__ float bf2f(ushort_t s) {
    uint_t u = ((uint_t)s) << 16;
    float f;
    __builtin_memcpy(&f, &u, 4);
    return f;
}
__device__ __forceinline__ ushort_t f2bf(float x) {
    uint_t u;
    __builtin_memcpy(&u, &x, 4);
    u += 0x7fffu + ((u >> 16) & 1u);   // RNE
    return (ushort_t)(u >> 16);
}

// ---- fast transcendentals (v_exp_f32 / v_rcp_f32; exact at saturation) ----
__device__ __forceinline__ float sigmoid_fast(float x) {
    return __builtin_amdgcn_rcpf(1.f + __expf(-x));
}
__device__ __forceinline__ float tanh_fast(float x) {
    const float e = __expf(-2.f * fabsf(x));          // in [0,1]
    const float r = (1.f - e) * __builtin_amdgcn_rcpf(1.f + e);
    return copysignf(r, x);
}

// ---- f32 -> bf16 bulk convert (8/thread; n multiple of 2048) ----
__global__ __launch_bounds__(256)
void cvt_f32_bf16(const float* __restrict__ in, ushort_t* __restrict__ out)
{
    const size_t i = ((size_t)blockIdx.x * 256 + threadIdx.x) * 8;
    const float4 v0 = *(const float4*)(in + i);
    const float4 v1 = *(const float4*)(in + i + 4);
    uint4 p;
    p.x = (uint_t)f2bf(v0.x) | ((uint_t)f2bf(v0.y) << 16);
    p.y = (uint_t)f2bf(v0.z) | ((uint_t)f2bf(v0.w) << 16);
    p.z = (uint_t)f2bf(v1.x) | ((uint_t)f2bf(v1.y) << 16);
    p.w = (uint_t)f2bf(v1.z) | ((uint_t)f2bf(v1.w) << 16);
    *(uint4*)(out + i) = p;
}

// Gate-major [4*C][K] f32 -> cell-major permuted bf16: Wp[P=c*4+g][k]
// (used for W_ih -> gx_p layout: gates of cell c at gx[c*4+g])
__global__ __launch_bounds__(256)
void permute_gate_rows(const float* __restrict__ W, ushort_t* __restrict__ Wp, int K)
{
    const int P = blockIdx.x;               // 0..2047
    const int c = P >> 2, g = P & 3;
    const float* src = W + (size_t)(g * CELL_D + c) * K;
    ushort_t* dst = Wp + (size_t)P * K;
    for (int k = threadIdx.x; k < K; k += 256) dst[k] = f2bf(src[k]);
}

// W_hh permute for the 256-block scan's lane->cell mapping:
// global row j*64 + t*16 + q*4 + r  <-  W_hh[gate r][cell j*16 + t*4 + q]
// Wave w(=t) lane (q,s): acc reg r = gate r of cell j*16 + w*4 + q, so the
// four q-lanes of a wave hold 4 CONTIGUOUS cells (shfl-packed for 8B stores).
__global__ __launch_bounds__(256)
void permute_whh_rows(const float* __restrict__ W, ushort_t* __restrict__ Wp, int K)
{
    const int P = blockIdx.x;               // 0..2047
    const int blk = P >> 6, rl = P & 63;
    const int t = rl >> 4, qq = (rl >> 2) & 3, r = rl & 3;
    const float* src = W + (size_t)(r * CELL_D + blk * 16 + t * 4 + qq) * K;
    ushort_t* dst = Wp + (size_t)P * K;
    for (int k = threadIdx.x; k < K; k += 256) dst[k] = f2bf(src[k]);
}

__global__ __launch_bounds__(256)
void permute_bias(const float* __restrict__ b, float* __restrict__ bp)
{
    const int P = blockIdx.x * 256 + threadIdx.x;   // grid 8
    bp[P] = b[(P & 3) * CELL_D + (P >> 2)];
}

// ---- MFMA bf16 GEMM: C[m][n] = sum_k A[m][k]*B[n][k] + bias[n] ----
// 128x128 tile, BK=32, 4 waves, 4x4 16x16x32 frags/wave.
// OUT_MODE: 0 = f32, 1 = bf16+ReLU, 2 = bf16 linear
template<int OUT_MODE>
__global__ __launch_bounds__(256)
void gemm_mfma_nt(const ushort_t* __restrict__ A, const ushort_t* __restrict__ B,
                  const float* __restrict__ bias, void* __restrict__ out_,
                  int N, int K)
{
    __shared__ __align__(16) ushort_t As[128 * 32];
    __shared__ __align__(16) ushort_t Bs[128 * 32];
    const int tid  = threadIdx.x;
    const int lane = tid & 63;
    const int wid  = tid >> 6;
    const int wr   = (wid >> 1) * 64;
    const int wc   = (wid & 1) * 64;
    const int m0 = blockIdx.y * 128;
    const int n0 = blockIdx.x * 128;

    const int srow = tid >> 2;
    const int sv   = tid & 3;
    const int fr   = lane & 15;
    const int fo   = lane >> 4;

    f32x4 acc[4][4];
#pragma unroll
    for (int i = 0; i < 4; ++i)
#pragma unroll
        for (int j = 0; j < 4; ++j) acc[i][j] = (f32x4){0.f, 0.f, 0.f, 0.f};

    const ushort_t* Apt = A + (size_t)(m0 + srow) * K + sv * 8;
    const ushort_t* Bpt = B + (size_t)(n0 + srow) * K + sv * 8;
    uint4* As4 = (uint4*)As;
    uint4* Bs4 = (uint4*)Bs;
    const bf16x8* Af = (const bf16x8*)As;
    const bf16x8* Bf = (const bf16x8*)Bs;

    for (int k0 = 0; k0 < K; k0 += 32) {
        const uint4 a0 = *(const uint4*)(Apt + k0);
        const uint4 a1 = *(const uint4*)(Apt + (size_t)64 * K + k0);
        const uint4 b0 = *(const uint4*)(Bpt + k0);
        const uint4 b1 = *(const uint4*)(Bpt + (size_t)64 * K + k0);
        __syncthreads();
        As4[srow * 4 + sv]        = a0;
        As4[(64 + srow) * 4 + sv] = a1;
        Bs4[srow * 4 + sv]        = b0;
        Bs4[(64 + srow) * 4 + sv] = b1;
        __syncthreads();

        bf16x8 av[4], bv[4];
#pragma unroll
        for (int m = 0; m < 4; ++m) av[m] = Af[(wr + m * 16 + fr) * 4 + fo];
#pragma unroll
        for (int n = 0; n < 4; ++n) bv[n] = Bf[(wc + n * 16 + fr) * 4 + fo];
#pragma unroll
        for (int m = 0; m < 4; ++m)
#pragma unroll
            for (int n = 0; n < 4; ++n)
                acc[m][n] = __builtin_amdgcn_mfma_f32_16x16x32_bf16(
                    av[m], bv[n], acc[m][n], 0, 0, 0);
    }

#pragma unroll
    for (int n = 0; n < 4; ++n) {
        const int col = n0 + wc + n * 16 + fr;
        const float bvv = bias[col];
#pragma unroll
        for (int m = 0; m < 4; ++m) {
            const int row0 = m0 + wr + m * 16 + fo * 4;
#pragma unroll
            for (int r = 0; r < 4; ++r) {
                const float v = acc[m][n][r] + bvv;
                if constexpr (OUT_MODE == 1)
                    ((ushort_t*)out_)[(size_t)(row0 + r) * N + col] = f2bf(fmaxf(v, 0.f));
                else if constexpr (OUT_MODE == 2)
                    ((ushort_t*)out_)[(size_t)(row0 + r) * N + col] = f2bf(v);
                else
                    ((float*)out_)[(size_t)(row0 + r) * N + col] = v;
            }
        }
    }
}

// ---- h-read pipeline helpers (quarter = 4 K-steps, 8x16B loads) ----
__device__ __forceinline__ void loadq(uint4 (&d0)[4], uint4 (&d1)[4],
                                      const ushort_t* hr0, const ushort_t* hr1,
                                      int base)
{
#pragma unroll
    for (int j = 0; j < 4; ++j) {
        d0[j] = *(const uint4*)(hr0 + (base + j) * 32);
        d1[j] = *(const uint4*)(hr1 + (base + j) * 32);
    }
}

// single 16-row tile (wave's own): 4 ks x {1 ds_read + 2 MFMA}
__device__ __forceinline__ void compq(const uint4 (&d0)[4], const uint4 (&d1)[4],
                                      const char* wsrow, int q16, int xmask,
                                      int base, f32x4& acc0, f32x4& acc1)
{
#pragma unroll
    for (int j = 0; j < 4; ++j) {
        bf16x8 hv0, hv1;
        __builtin_memcpy(&hv0, &d0[j], 16);
        __builtin_memcpy(&hv1, &d1[j], 16);
        const int koff = ((base + j) * 64 + q16) ^ xmask;
        const bf16x8 av = *(const bf16x8*)(wsrow + koff);
        acc0 = __builtin_amdgcn_mfma_f32_16x16x32_bf16(av, hv0, acc0, 0, 0, 0);
        acc1 = __builtin_amdgcn_mfma_f32_16x16x32_bf16(av, hv1, acc1, 0, 0, 0);
    }
}

// ---- persistent LSTM scan, 256 blocks x 256 threads (ALL CUs) ----
// REVERT to the round-12 optimum (best measured). Round 13 (2 w/SIMD) was
// neutral; round 14 (fused GEMM workers) regressed 26% — the scan is
// latency-critical and any co-resident memory traffic inflates all 512
// serial LLC rendezvous.
// One cleanup vs r12: MONOTONE FLAGS across chunks (flag = completed global
// step count; producer stores t0+tl+1, consumer waits >= t0+tl) -> the
// per-chunk bar memset and its serialization are gone (single memset before
// chunk 0). Stale flags from chunk ci are <= t0+Tc-1 < any ci+1 target.
__global__ __launch_bounds__(256)
void lstm_scan(const ushort_t* __restrict__ gx_p,   // [Tc*256][2048] bf16 (P-cols)
               const ushort_t* __restrict__ Whh_p,  // [2048][512] bf16 (scan permute)
               const float* __restrict__ b_hh,      // [2048] f32 gate-major
               const float* __restrict__ masks_c,   // [Tc*256]
               const ushort_t* h_init,              // [256][512] bf16
               float* __restrict__ c_state,         // [256][512] f32 in/out
               ushort_t* hid,                       // [Tc][256][512] bf16 out
               float* __restrict__ hT_f32,
               int Tc, int is_last, int t0,         // t0 = global step base
               uint_t* __restrict__ bar)            // flags[8][32], 128B/chain
{
    __shared__ __align__(16) ushort_t Ws[64 * 512];   // 64 KiB, XOR-swizzled

    const int tid  = threadIdx.x;
    const int lane = tid & 63;
    const int w    = tid >> 6;            // wave 0..3 -> P-row tile w of slice
    const int q    = lane >> 4;           // 0..3
    const int s    = lane & 15;           // batch col within group
    const int x    = blockIdx.x & 7;      // batch group (XCD-heuristic spread)
    const int j    = blockIdx.x >> 3;     // cell slice 0..31
    const int xmask = (s & 7) << 4;       // LDS XOR swizzle
    const int q16  = q * 16;
    const int cell = j * 16 + w * 4 + q;  // lane's single cell

    // ---- W slice j -> LDS (swizzled); rows [j*64, +64), stride 1024 B ----
    for (int idx = tid; idx < 64 * 64; idx += 256) {
        const int row = idx >> 6;
        const int c16 = idx & 63;
        const uint4 v = *(const uint4*)(Whh_p + (size_t)(j * 64 + row) * CELL_D + c16 * 8);
        *(uint4*)((char*)Ws + row * 1024 + ((c16 * 16) ^ ((row & 7) << 4))) = v;
    }

    const int b0 = x * 32 + s;            // nfl=0 batch row
    const int b1 = b0 + 16;               // nfl=1

    // ---- per-lane state ----
    float creg0 = c_state[(size_t)b0 * CELL_D + cell];
    float creg1 = c_state[(size_t)b1 * CELL_D + cell];
    float bh[4];
#pragma unroll
    for (int r = 0; r < 4; ++r) bh[r] = b_hh[r * CELL_D + cell];

    // ---- gx/mask prefetch (gates of lane's cell for b0,b1) ----
    float mv0, mv1;
    uint2 gxv[2];
    auto prefetch_step = [&](int TL) {
        const ushort_t* g0 = gx_p + ((size_t)TL * BATCH + b0) * GATE_D + cell * 4;
        gxv[0] = *(const uint2*)g0;
        gxv[1] = *(const uint2*)(g0 + (size_t)16 * GATE_D);
        mv0 = masks_c[(size_t)TL * BATCH + b0];
        mv1 = masks_c[(size_t)TL * BATCH + b1];
    };

    const char* wsrow = (const char*)Ws + (w * 16 + s) * 1024;
    __syncthreads();                      // Ws staging complete

    for (int tl = 0; tl < Tc; ++tl) {
        const ushort_t* hp = (tl == 0) ? h_init
                                       : hid + (size_t)(tl - 1) * BATCH * CELL_D;
        const ushort_t* hr0 = hp + (size_t)b0 * CELL_D + q * 8;
        const ushort_t* hr1 = hp + (size_t)b1 * CELL_D + q * 8;

        // ---- per-quarter flag-group wait (flag >= t0+tl: step t0+tl-1 done) ----
        uint64_t ready = 0;
        const uint_t tgt_in = (uint_t)(t0 + tl);
        auto waitg = [&](int g) {
            const uint64_t need = 0xFFull << (g * 8);
            if ((ready & need) != need) {
                const uint_t* fp = bar + x * 32 + (lane & 31);
                for (;;) {
                    uint_t v;
                    asm volatile("global_load_dword %0, %1, off sc0 sc1\n\t"
                                 "s_waitcnt vmcnt(0)"
                                 : "=v"(v) : "v"(fp) : "memory");
                    ready = __ballot((int)(v >= tgt_in)) & 0xFFFFFFFFull;
                    if ((ready & need) == need) break;
                    __builtin_amdgcn_s_sleep(1);
                }
            }
            asm volatile("" ::: "memory");
        };

        f32x4 acc0 = (f32x4){0.f, 0.f, 0.f, 0.f};
        f32x4 acc1 = (f32x4){0.f, 0.f, 0.f, 0.f};

        // ---- pipelined: waitg(g) -> loadq(g) -> compq(g-1) ----
        uint4 A0[4], A1[4], B0[4], B1[4];
        if (tl) waitg(0);
        loadq(A0, A1, hr0, hr1, 0);
        prefetch_step(tl);
        if (tl) waitg(1);
        loadq(B0, B1, hr0, hr1, 4);
        compq(A0, A1, wsrow, q16, xmask, 0, acc0, acc1);
        if (tl) waitg(2);
        loadq(A0, A1, hr0, hr1, 8);
        compq(B0, B1, wsrow, q16, xmask, 4, acc0, acc1);
        if (tl) waitg(3);
        loadq(B0, B1, hr0, hr1, 12);
        compq(A0, A1, wsrow, q16, xmask, 8, acc0, acc1);
        compq(B0, B1, wsrow, q16, xmask, 12, acc0, acc1);

        // ---- cell update (mask post-MFMA; exact for keep in {0,1}) ----
        const float keep0 = (mv0 > 0.5f) ? 0.f : 1.f;
        const float keep1 = (mv1 > 0.5f) ? 0.f : 1.f;
        const ushort_t* gp0 = (const ushort_t*)&gxv[0];
        const ushort_t* gp1 = (const ushort_t*)&gxv[1];

        const float gi0 = fmaf(acc0[0], keep0, bf2f(gp0[0]) + bh[0]);
        const float gf0 = fmaf(acc0[1], keep0, bf2f(gp0[1]) + bh[1]);
        const float gg0 = fmaf(acc0[2], keep0, bf2f(gp0[2]) + bh[2]);
        const float go0 = fmaf(acc0[3], keep0, bf2f(gp0[3]) + bh[3]);
        const float cn0 = sigmoid_fast(gf0) * (creg0 * keep0)
                        + sigmoid_fast(gi0) * tanh_fast(gg0);
        const float hn0 = sigmoid_fast(go0) * tanh_fast(cn0);
        creg0 = cn0;

        const float gi1 = fmaf(acc1[0], keep1, bf2f(gp1[0]) + bh[0]);
        const float gf1 = fmaf(acc1[1], keep1, bf2f(gp1[1]) + bh[1]);
        const float gg1 = fmaf(acc1[2], keep1, bf2f(gp1[2]) + bh[2]);
        const float go1 = fmaf(acc1[3], keep1, bf2f(gp1[3]) + bh[3]);
        const float cn1 = sigmoid_fast(gf1) * (creg1 * keep1)
                        + sigmoid_fast(gi1) * tanh_fast(gg1);
        const float hn1 = sigmoid_fast(go1) * tanh_fast(cn1);
        creg1 = cn1;

        // ---- shfl-pack 4 q-lanes' contiguous cells -> 8B stores (q==0) ----
        const uint_t hv01 = (uint_t)f2bf(hn0) | ((uint_t)f2bf(hn1) << 16);
        const uint_t vA = (uint_t)__shfl((int)hv01, s + 16);
        const uint_t vB = (uint_t)__shfl((int)hv01, s + 32);
        const uint_t vC = (uint_t)__shfl((int)hv01, s + 48);
        if (q == 0) {
            u32x2 r0, r1;
            r0[0] = (hv01 & 0xFFFFu) | (vA << 16);
            r0[1] = (vB & 0xFFFFu) | (vC << 16);
            r1[0] = (hv01 >> 16) | (vA & 0xFFFF0000u);
            r1[1] = (vB >> 16) | (vC & 0xFFFF0000u);
            ushort_t* d0 = hid + (size_t)tl * BATCH * CELL_D
                         + (size_t)b0 * CELL_D + j * 16 + w * 4;
            ushort_t* d1 = hid + (size_t)tl * BATCH * CELL_D
                         + (size_t)b1 * CELL_D + j * 16 + w * 4;
            asm volatile("global_store_dwordx2 %0, %1, off sc0 sc1"
                         :: "v"(d0), "v"(r0) : "memory");
            asm volatile("global_store_dwordx2 %0, %1, off sc0 sc1"
                         :: "v"(d1), "v"(r1) : "memory");
        }
        if (is_last && tl == Tc - 1) {
            hT_f32[(size_t)b0 * CELL_D + cell] = hn0;
            hT_f32[(size_t)b1 * CELL_D + cell] = hn1;
        }

        if (tl == Tc - 1) break;   // last step: no release needed

        // ---- release: drain own stores, block barrier, tid0 sets flag ----
        asm volatile("s_waitcnt vmcnt(0)" ::: "memory");
        __builtin_amdgcn_s_barrier();
        if (tid == 0) {
            const uint_t tgt = (uint_t)(t0 + tl + 1);
            asm volatile("global_store_dword %0, %1, off sc0 sc1"
                         :: "v"(bar + x * 32 + j), "v"(tgt) : "memory");
        }
    }

    // ---- write back c ----
    c_state[(size_t)b0 * CELL_D + cell] = creg0;
    c_state[(size_t)b1 * CELL_D + cell] = creg1;
}

// means = tanh(h @ W_mean^T + b_mean); log_std broadcast. h is bf16.
__global__ __launch_bounds__(256)
void mean_head(const ushort_t* __restrict__ hiddens, const float* __restrict__ W_mean,
               const float* __restrict__ b_mean, const float* __restrict__ log_std,
               float* __restrict__ means_out, float* __restrict__ logstd_out)
{
    __shared__ float Wm[8][516];
    const int tid = threadIdx.x;
#pragma unroll
    for (int i = 0; i < 16; ++i) {
        int idx = i * 256 + tid;
        Wm[idx >> 9][idx & 511] = W_mean[idx];
    }
    __syncthreads();
    const int r = tid >> 3, a = tid & 7;
    const size_t m = (size_t)blockIdx.x * 32 + r;
    const ushort_t* hp = hiddens + m * CELL_D;
    float acc = 0.f;
#pragma unroll 2
    for (int k8 = 0; k8 < 64; ++k8) {
        const uint4 v = *(const uint4*)(hp + k8 * 8);
        const ushort_t* pv = (const ushort_t*)&v;
        const float* wv = &Wm[a][k8 * 8];
#pragma unroll
        for (int e = 0; e < 8; ++e) acc = fmaf(bf2f(pv[e]), wv[e], acc);
    }
    means_out[m * ACT_D + a]  = tanhf(acc + b_mean[a]);
    logstd_out[m * ACT_D + a] = log_std[a];
}

extern "C" void kernel_launch(void* const* d_in, const int* in_sizes, int n_in,
                              void* d_out, int out_size, void* d_ws, size_t ws_size,
                              hipStream_t stream)
{
    const float* xs     = (const float*)d_in[0];
    const float* h0     = (const float*)d_in[1];
    const float* c0     = (const float*)d_in[2];
    const float* masks  = (const float*)d_in[3];
    const float* W_in   = (const float*)d_in[4];
    const float* b_in   = (const float*)d_in[5];
    const float* W_ih   = (const float*)d_in[6];
    const float* b_ih   = (const float*)d_in[7];
    const float* W_hh   = (const float*)d_in[8];
    const float* b_hh   = (const float*)d_in[9];
    const float* W_mean = (const float*)d_in[10];
    const float* b_mean = (const float*)d_in[11];
    const float* lstd   = (const float*)d_in[12];

    const int M = T_STEPS * BATCH;
    const size_t stateB = (size_t)BATCH * CELL_D * sizeof(float);   // 512 KiB

    const size_t szWhh  = (size_t)GATE_D * CELL_D * 2;   // 2 MiB
    const size_t szWih  = (size_t)GATE_D * HID_D * 2;    // 4 MiB
    const size_t szWin  = (size_t)HID_D * OBS_D * 2;     // 128 KiB
    const size_t szH0b  = (size_t)BATCH * CELL_D * 2;    // 256 KiB
    const size_t szBih  = (size_t)GATE_D * 4;            // 8 KiB
    const size_t szBar  = 1024;
    const size_t fixed  = szWhh + szWih + szWin + szH0b + szBih + szBar + stateB;

    const size_t per_tc = (size_t)BATCH * GATE_D * 2     // gx_p bf16: 1 MiB
                        + (size_t)BATCH * CELL_D * 2     // hid bf16
                        + (size_t)BATCH * HID_D * 2      // E bf16
                        + (size_t)BATCH * OBS_D * 2;     // xs_b
    int Tc = T_STEPS;
    while (Tc > 2 && fixed + per_tc * (size_t)Tc > ws_size) Tc >>= 1;

    char* p = (char*)d_ws;
    ushort_t* Whh_p = (ushort_t*)p;              p += szWhh;
    ushort_t* Wih_p = (ushort_t*)p;              p += szWih;
    ushort_t* Win_b = (ushort_t*)p;              p += szWin;
    ushort_t* h0b   = (ushort_t*)p;              p += szH0b;
    float*    bihp  = (float*)p;                 p += szBih;
    uint_t*   bar   = (uint_t*)p;                p += szBar;
    float*    c_state = (float*)p;               p += stateB;
    ushort_t* gx_p  = (ushort_t*)p;              p += (size_t)Tc * BATCH * GATE_D * 2;
    ushort_t* hid   = (ushort_t*)p;              p += (size_t)Tc * BATCH * CELL_D * 2;
    ushort_t* E     = (ushort_t*)p;              p += (size_t)Tc * BATCH * HID_D * 2;
    ushort_t* xs_b  = (ushort_t*)p;

    float* means_out  = (float*)d_out;
    float* logstd_out = means_out + (size_t)M * ACT_D;
    float* hT_out     = logstd_out + (size_t)M * ACT_D;
    float* cT_out     = hT_out + (size_t)BATCH * CELL_D;

    // ---- one-shot converts / permutes / state init ----
    permute_whh_rows<<<GATE_D, 256, 0, stream>>>(W_hh, Whh_p, CELL_D);
    permute_gate_rows<<<GATE_D, 256, 0, stream>>>(W_ih, Wih_p, HID_D);
    cvt_f32_bf16<<<(HID_D * OBS_D) / 2048, 256, 0, stream>>>(W_in, Win_b);
    cvt_f32_bf16<<<(BATCH * CELL_D) / 2048, 256, 0, stream>>>(h0, h0b);
    permute_bias<<<GATE_D / 256, 256, 0, stream>>>(b_ih, bihp);
    hipMemcpyAsync(c_state, c0, stateB, hipMemcpyDeviceToDevice, stream);
    hipMemsetAsync(bar, 0, 1024, stream);   // once: flags are monotone across chunks

    const int chunks = T_STEPS / Tc;
    for (int ci = 0; ci < chunks; ++ci) {
        const int t0 = ci * Tc;
        const int Mc = Tc * BATCH;

        cvt_f32_bf16<<<(Mc * OBS_D) / 2048, 256, 0, stream>>>(
            xs + (size_t)t0 * BATCH * OBS_D, xs_b);

        gemm_mfma_nt<1><<<dim3(HID_D / 128, Mc / 128), 256, 0, stream>>>(
            xs_b, Win_b, b_in, E, HID_D, OBS_D);

        gemm_mfma_nt<2><<<dim3(GATE_D / 128, Mc / 128), 256, 0, stream>>>(
            E, Wih_p, bihp, gx_p, GATE_D, HID_D);

        const ushort_t* h_init = (ci == 0) ? h0b
                               : hid + (size_t)(Tc - 1) * BATCH * CELL_D;
        lstm_scan<<<SCAN_BLOCKS, 256, 0, stream>>>(
            gx_p, Whh_p, b_hh, masks + (size_t)t0 * BATCH, h_init,
            c_state, hid, hT_out, Tc, (ci == chunks - 1) ? 1 : 0, t0, bar);

        mean_head<<<Mc / 32, 256, 0, stream>>>(
            hid, W_mean, b_mean, lstd,
            means_out + (size_t)t0 * BATCH * ACT_D,
            logstd_out + (size_t)t0 * BATCH * ACT_D);
    }

    hipMemcpyAsync(cT_out, c_state, stateB, hipMemcpyDeviceToDevice, stream);
}